// Round 13
// baseline (2211.910 us; speedup 1.0000x reference)
//
#include <hip/hip_runtime.h>

#define BS   4096   // BATCH*SEQ
#define SEQL 2048
#define DM   1024
#define DH   4096
#define NV   32000

using u16 = unsigned short;

typedef __attribute__((ext_vector_type(8))) short bf16x8;
typedef __attribute__((ext_vector_type(4))) float f32x4;

__device__ __forceinline__ u16 f2b(float f) {
  union { float f; unsigned u; } c; c.f = f;
  unsigned u = c.u;
  u = (u + 0x7FFFu + ((u >> 16) & 1u)) >> 16;
  return (u16)u;
}

__device__ __forceinline__ void gld16(const u16* g, u16* l) {
  __builtin_amdgcn_global_load_lds(
      (__attribute__((address_space(1))) void*)(void*)const_cast<u16*>(g),
      (__attribute__((address_space(3))) void*)l, 16, 0, 0);
}

// ---------------- embed ----------------
__global__ __launch_bounds__(256) void k_embed(const int* __restrict__ tok,
                                               const float* __restrict__ emb,
                                               float* __restrict__ x) {
  const long row = blockIdx.x;
  const long e = tok[row];
  ((float4*)(x + row * DM))[threadIdx.x] = ((const float4*)(emb + e * DM))[threadIdx.x];
}

// ---------------- f32 -> bf16 convert ----------------
__global__ __launch_bounds__(256) void k_cvt(const float* __restrict__ in,
                                             u16* __restrict__ out, int n4) {
  int i = blockIdx.x * 256 + threadIdx.x;
  if (i < n4) {
    float4 v = ((const float4*)in)[i];
    ushort4 o;
    o.x = f2b(v.x); o.y = f2b(v.y); o.z = f2b(v.z); o.w = f2b(v.w);
    ((ushort4*)out)[i] = o;
  }
}

// ---------------- LayerNorm ----------------
__global__ __launch_bounds__(256) void k_ln(const float* __restrict__ x,
                                            const float* __restrict__ g,
                                            const float* __restrict__ b,
                                            u16* __restrict__ out) {
  const long row = blockIdx.x;
  const int t = threadIdx.x;
  float4 v = ((const float4*)(x + row * DM))[t];
  float s  = v.x + v.y + v.z + v.w;
  float q2 = v.x*v.x + v.y*v.y + v.z*v.z + v.w*v.w;
#pragma unroll
  for (int o = 1; o < 64; o <<= 1) { s += __shfl_xor(s, o); q2 += __shfl_xor(q2, o); }
  __shared__ float rs_[4], rq_[4];
  const int lane = t & 63, wid = t >> 6;
  if (lane == 0) { rs_[wid] = s; rq_[wid] = q2; }
  __syncthreads();
  s  = rs_[0] + rs_[1] + rs_[2] + rs_[3];
  q2 = rq_[0] + rq_[1] + rq_[2] + rq_[3];
  const float mu   = s * (1.f / 1024.f);
  const float var  = q2 * (1.f / 1024.f) - mu * mu;
  const float rstd = rsqrtf(var + 1e-5f);
  float4 gg = ((const float4*)g)[t];
  float4 bb = ((const float4*)b)[t];
  ushort4 o;
  o.x = f2b((v.x - mu) * rstd * gg.x + bb.x);
  o.y = f2b((v.y - mu) * rstd * gg.y + bb.y);
  o.z = f2b((v.z - mu) * rstd * gg.z + bb.z);
  o.w = f2b((v.w - mu) * rstd * gg.w + bb.w);
  ((ushort4*)(out + row * DM))[t] = o;
}

// ---------------- 64x64 tiled transpose, optional f32->bf16 ----------------
__device__ __forceinline__ u16 to_b16(float v) { return f2b(v); }
__device__ __forceinline__ u16 to_b16(u16 v)   { return v; }

template <typename T>
__global__ __launch_bounds__(256) void k_transpose64(const T* __restrict__ in,
                                                     u16* __restrict__ out,
                                                     int R, int C, long inz, long outz) {
  __shared__ u16 tile[64][65];
  const T* ip = in + (long)blockIdx.z * inz;
  u16* op = out + (long)blockIdx.z * outz;
  const int tx = threadIdx.x & 63, ty = threadIdx.x >> 6;
  const long c0 = (long)blockIdx.x * 64, r0 = (long)blockIdx.y * 64;
#pragma unroll
  for (int i = 0; i < 16; ++i)
    tile[ty + i * 4][tx] = to_b16(ip[(r0 + ty + i * 4) * C + c0 + tx]);
  __syncthreads();
#pragma unroll
  for (int i = 0; i < 16; ++i)
    op[(c0 + ty + i * 4) * R + r0 + tx] = tile[tx][ty + i * 4];
}

// ---------------- causal row softmax (work limited to <= r) ----------------
__global__ __launch_bounds__(256) void k_softmax(const float* __restrict__ sc,
                                                 u16* __restrict__ at) {
  const int r = blockIdx.x;
  const long z = blockIdx.y;
  const int t = threadIdx.x;
  const float* row = sc + (z * SEQL + r) * SEQL;
  u16* orow = at + (z * SEQL + r) * SEQL;
  const int ni = (r >> 8) + 1;
  float vals[8];
  float mx = -3.4e38f;
  for (int i = 0; i < ni; ++i) {
    int c = i * 256 + t;
    float v = (c <= r) ? row[c] : -3.4e38f;
    vals[i] = v;
    mx = fmaxf(mx, v);
  }
#pragma unroll
  for (int o = 1; o < 64; o <<= 1) mx = fmaxf(mx, __shfl_xor(mx, o));
  __shared__ float rm[4], rsum[4];
  const int lane = t & 63, wid = t >> 6;
  if (lane == 0) rm[wid] = mx;
  __syncthreads();
  mx = fmaxf(fmaxf(rm[0], rm[1]), fmaxf(rm[2], rm[3]));
  float sum = 0.f;
  for (int i = 0; i < ni; ++i) {
    int c = i * 256 + t;
    float e = (c <= r) ? __expf(vals[i] - mx) : 0.f;
    vals[i] = e;
    sum += e;
  }
#pragma unroll
  for (int o = 1; o < 64; o <<= 1) sum += __shfl_xor(sum, o);
  if (lane == 0) rsum[wid] = sum;
  __syncthreads();
  sum = rsum[0] + rsum[1] + rsum[2] + rsum[3];
  const float inv = 1.f / sum;
  for (int i = 0; i < ni; ++i) orow[i * 256 + t] = f2b(vals[i] * inv);
}

// ---------------- 128x128 bf16 GEMM, BK=128 (four [128][32] half-tiles) -----
// Quarters barrier frequency vs BK=32 (one barrier pair per 128 K-elems).
// Conflict-free 64B-row half-tile layout; 64KB LDS (2 blocks/CU); ascending-k
// accumulation -> bit-identical output.
template <int EPI, bool BIAS, bool LRELU, int CAUSAL, bool XOUT>
__global__ __launch_bounds__(256, 2) void k_gemm_bt(
    const u16* __restrict__ A, const u16* __restrict__ B, void* __restrict__ C,
    const float* __restrict__ bias, u16* __restrict__ xb, int K, int N,
    long sAz, long sBz, long sCz, float scale) {
  __shared__ u16 lA[4][128 * 32];
  __shared__ u16 lB[4][128 * 32];
  const int t = threadIdx.x;
  const long z = blockIdx.z;
  const long row0 = (long)blockIdx.x * 128;
  const long col0 = (long)blockIdx.y * 128;
  if (CAUSAL == 1 && col0 > row0 + 127) return;
  const int Klim = (CAUSAL == 2) ? min(K, (int)row0 + 128) : K;
  const u16* Ab = A + z * sAz;
  const u16* Bb = B + z * sBz;

  const int rr = t >> 2;           // 0..63
  const int c8 = (t & 3) * 8;      // 0,8,16,24
  const u16* gA0 = Ab + (row0 + rr) * K + c8;
  const u16* gA1 = Ab + (row0 + 64 + rr) * K + c8;
  const u16* gB0 = Bb + (col0 + rr) * K + c8;
  const u16* gB1 = Bb + (col0 + 64 + rr) * K + c8;
  const int so0 = rr * 32 + c8;
  const int so1 = (64 + rr) * 32 + c8;

  const int lane = t & 63;
  const int w = t >> 6;
  const int wr = (w >> 1) * 64, wc = (w & 1) * 64;
  const int fr = lane & 15;
  const int fk = (lane >> 4) * 8;

  f32x4 acc[4][4] = {};

  for (int k0 = 0; k0 < Klim; k0 += 128) {
#pragma unroll
    for (int q = 0; q < 4; ++q) {
      gld16(gA0 + k0 + q * 32, &lA[q][so0]);
      gld16(gA1 + k0 + q * 32, &lA[q][so1]);
      gld16(gB0 + k0 + q * 32, &lB[q][so0]);
      gld16(gB1 + k0 + q * 32, &lB[q][so1]);
    }
    __syncthreads();
#pragma unroll
    for (int kh = 0; kh < 4; ++kh) {
      bf16x8 av[4], bv[4];
#pragma unroll
      for (int m = 0; m < 4; ++m) av[m] = *(const bf16x8*)&lA[kh][(wr + m * 16 + fr) * 32 + fk];
#pragma unroll
      for (int n = 0; n < 4; ++n) bv[n] = *(const bf16x8*)&lB[kh][(wc + n * 16 + fr) * 32 + fk];
#pragma unroll
      for (int m = 0; m < 4; ++m)
#pragma unroll
        for (int n = 0; n < 4; ++n)
          acc[m][n] = __builtin_amdgcn_mfma_f32_16x16x32_bf16(av[m], bv[n], acc[m][n], 0, 0, 0);
    }
    __syncthreads();
  }

  const int er = (lane >> 4) * 4;
  const int ec = lane & 15;
#pragma unroll
  for (int m = 0; m < 4; ++m) {
#pragma unroll
    for (int n = 0; n < 4; ++n) {
#pragma unroll
      for (int j = 0; j < 4; ++j) {
        long r = row0 + wr + m * 16 + er + j;
        long c = col0 + wc + n * 16 + ec;
        float v = acc[m][n][j] * scale;
        if (BIAS)  v += bias[c];
        if (LRELU) v = v > 0.f ? v : 0.01f * v;
        long idx = z * sCz + r * (long)N + c;
        if (EPI == 0)      ((float*)C)[idx] = v;
        else if (EPI == 1) ((u16*)C)[idx] = f2b(v);
        else {
          float nv = ((float*)C)[idx] + v;
          ((float*)C)[idx] = nv;
          if (XOUT) xb[idx] = f2b(nv);
        }
      }
    }
  }
}

// ---------------- 256x256 BK=64 8-wave bf16 GEMM, m201-faithful phases ------
// (R8 configuration — best verified for the 1-block/CU 256² shapes.)
template <int EPI, bool BIAS, bool LRELU>
__device__ __forceinline__ void g256_body(
    u16* S, const u16* __restrict__ A, const u16* __restrict__ B,
    void* __restrict__ C, const float* __restrict__ bias, int K, int N, float scale) {
  char* Sc = (char*)S;
  const int t = threadIdx.x;
  const int lane = t & 63;
  const int w = t >> 6;
  const int wr = w >> 2;           // 0..1  (M half)
  const int wc = w & 3;            // 0..3  (N quarter)
  const long row0 = (long)blockIdx.x * 256;
  const long col0 = (long)blockIdx.y * 256;
  const int nt = K >> 6;

  int srow[2], scol[2], ldsb[2];
#pragma unroll
  for (int i = 0; i < 2; ++i) {
    int d = t * 16 + i * 8192;
    int dx = d ^ (((d >> 7) & 3) << 4);
    srow[i] = dx >> 6;
    scol[i] = (dx & 63) >> 1;
    ldsb[i] = d;
  }
  const u16* Abase = A + row0 * (long)K;
  const u16* Bbase = B + col0 * (long)K;

  auto stage = [&](int opb, int kh, int buf, int kb) {
#pragma unroll
    for (int i = 0; i < 2; ++i) {
      const u16* src = (opb ? Bbase : Abase) + (long)srow[i] * K + kb + kh * 32 + scol[i];
      u16* dst = &S[(buf * 4 + opb * 2 + kh) * 8192 + (ldsb[i] >> 1)];
      gld16(src, dst);
    }
  };

  const int fr = lane & 15;
  const int fky = lane >> 4;
  const int axor = ((fr >> 1) & 3) << 4;
  int aoff[8], boff[4];
#pragma unroll
  for (int m = 0; m < 8; ++m)
    aoff[m] = (((wr * 128 + m * 16 + fr) * 64) + fky * 16) ^ axor;
#pragma unroll
  for (int n = 0; n < 4; ++n)
    boff[n] = (((wc * 64 + n * 16 + fr) * 64) + fky * 16) ^ axor;

  f32x4 acc[8][4] = {};
  bf16x8 av0, av1, av2, av3;
  bf16x8 bX0, bX1, bX2, bX3, bY0, bY1, bY2, bY3;

#define RD_A(bb, kh, mh)                                                   \
  { const char* Ah_ = Sc + (bb) * 65536 + (kh) * 16384;                    \
    av0 = *(const bf16x8*)(Ah_ + aoff[(mh) * 4 + 0]);                      \
    av1 = *(const bf16x8*)(Ah_ + aoff[(mh) * 4 + 1]);                      \
    av2 = *(const bf16x8*)(Ah_ + aoff[(mh) * 4 + 2]);                      \
    av3 = *(const bf16x8*)(Ah_ + aoff[(mh) * 4 + 3]); }
#define RD_B(d0, d1, d2, d3, bb, kh)                                       \
  { const char* Bh_ = Sc + (bb) * 65536 + 32768 + (kh) * 16384;            \
    d0 = *(const bf16x8*)(Bh_ + boff[0]);                                  \
    d1 = *(const bf16x8*)(Bh_ + boff[1]);                                  \
    d2 = *(const bf16x8*)(Bh_ + boff[2]);                                  \
    d3 = *(const bf16x8*)(Bh_ + boff[3]); }
#define WAIT_LGKM()                                                        \
  asm volatile("s_waitcnt lgkmcnt(0)" ::: "memory");                       \
  __builtin_amdgcn_sched_barrier(0);
#define MF16(b0, b1, b2, b3, mh)                                                                     \
  __builtin_amdgcn_s_setprio(1);                                                                     \
  acc[(mh)*4+0][0] = __builtin_amdgcn_mfma_f32_16x16x32_bf16(av0, b0, acc[(mh)*4+0][0], 0, 0, 0);    \
  acc[(mh)*4+0][1] = __builtin_amdgcn_mfma_f32_16x16x32_bf16(av0, b1, acc[(mh)*4+0][1], 0, 0, 0);    \
  acc[(mh)*4+0][2] = __builtin_amdgcn_mfma_f32_16x16x32_bf16(av0, b2, acc[(mh)*4+0][2], 0, 0, 0);    \
  acc[(mh)*4+0][3] = __builtin_amdgcn_mfma_f32_16x16x32_bf16(av0, b3, acc[(mh)*4+0][3], 0, 0, 0);    \
  acc[(mh)*4+1][0] = __builtin_amdgcn_mfma_f32_16x16x32_bf16(av1, b0, acc[(mh)*4+1][0], 0, 0, 0);    \
  acc[(mh)*4+1][1] = __builtin_amdgcn_mfma_f32_16x16x32_bf16(av1, b1, acc[(mh)*4+1][1], 0, 0, 0);    \
  acc[(mh)*4+1][2] = __builtin_amdgcn_mfma_f32_16x16x32_bf16(av1, b2, acc[(mh)*4+1][2], 0, 0, 0);    \
  acc[(mh)*4+1][3] = __builtin_amdgcn_mfma_f32_16x16x32_bf16(av1, b3, acc[(mh)*4+1][3], 0, 0, 0);    \
  acc[(mh)*4+2][0] = __builtin_amdgcn_mfma_f32_16x16x32_bf16(av2, b0, acc[(mh)*4+2][0], 0, 0, 0);    \
  acc[(mh)*4+2][1] = __builtin_amdgcn_mfma_f32_16x16x32_bf16(av2, b1, acc[(mh)*4+2][1], 0, 0, 0);    \
  acc[(mh)*4+2][2] = __builtin_amdgcn_mfma_f32_16x16x32_bf16(av2, b2, acc[(mh)*4+2][2], 0, 0, 0);    \
  acc[(mh)*4+2][3] = __builtin_amdgcn_mfma_f32_16x16x32_bf16(av2, b3, acc[(mh)*4+2][3], 0, 0, 0);    \
  acc[(mh)*4+3][0] = __builtin_amdgcn_mfma_f32_16x16x32_bf16(av3, b0, acc[(mh)*4+3][0], 0, 0, 0);    \
  acc[(mh)*4+3][1] = __builtin_amdgcn_mfma_f32_16x16x32_bf16(av3, b1, acc[(mh)*4+3][1], 0, 0, 0);    \
  acc[(mh)*4+3][2] = __builtin_amdgcn_mfma_f32_16x16x32_bf16(av3, b2, acc[(mh)*4+3][2], 0, 0, 0);    \
  acc[(mh)*4+3][3] = __builtin_amdgcn_mfma_f32_16x16x32_bf16(av3, b3, acc[(mh)*4+3][3], 0, 0, 0);    \
  __builtin_amdgcn_s_setprio(0);

  // prologue: stage tile 0; wait kh0 halves (4 remain outstanding)
  stage(0, 0, 0, 0);
  stage(1, 0, 0, 0);
  stage(0, 1, 0, 0);
  stage(1, 1, 0, 0);
  asm volatile("s_waitcnt vmcnt(4)" ::: "memory");
  __builtin_amdgcn_s_barrier();

  int cur = 0;
  for (int tt = 0; tt < nt; ++tt) {
    const int knext = (tt + 1 < nt ? tt + 1 : tt) * 64;
    const int nx = cur ^ 1;
    // ph1: (kh0,mh0) — stage A-kh0 -> nxt
    RD_A(cur, 0, 0);
    RD_B(bX0, bX1, bX2, bX3, cur, 0);
    stage(0, 0, nx, knext);
    __builtin_amdgcn_s_barrier();
    WAIT_LGKM();
    MF16(bX0, bX1, bX2, bX3, 0);
    __builtin_amdgcn_s_barrier();
    // ph2: (kh0,mh1) — stage B-kh0 -> nxt
    RD_A(cur, 0, 1);
    stage(1, 0, nx, knext);
    __builtin_amdgcn_s_barrier();
    WAIT_LGKM();
    MF16(bX0, bX1, bX2, bX3, 1);
    asm volatile("s_waitcnt vmcnt(4)" ::: "memory");   // kh1(cur) landed
    __builtin_amdgcn_s_barrier();
    // ph3: (kh1,mh0) — stage A-kh1 -> nxt
    RD_A(cur, 1, 0);
    RD_B(bY0, bY1, bY2, bY3, cur, 1);
    stage(0, 1, nx, knext);
    __builtin_amdgcn_s_barrier();
    WAIT_LGKM();
    MF16(bY0, bY1, bY2, bY3, 0);
    __builtin_amdgcn_s_barrier();
    // ph4: (kh1,mh1) — stage B-kh1 -> nxt
    RD_A(cur, 1, 1);
    stage(1, 1, nx, knext);
    __builtin_amdgcn_s_barrier();
    WAIT_LGKM();
    MF16(bY0, bY1, bY2, bY3, 1);
    asm volatile("s_waitcnt vmcnt(4)" ::: "memory");   // kh0(next) landed
    __builtin_amdgcn_s_barrier();
    cur = nx;
  }
  asm volatile("s_waitcnt vmcnt(0)" ::: "memory");
#undef RD_A
#undef RD_B
#undef WAIT_LGKM
#undef MF16

  const int er = (lane >> 4) * 4;
  const int ec = lane & 15;
#pragma unroll
  for (int m = 0; m < 8; ++m) {
#pragma unroll
    for (int n = 0; n < 4; ++n) {
#pragma unroll
      for (int j = 0; j < 4; ++j) {
        long r = row0 + wr * 128 + m * 16 + er + j;
        long c = col0 + wc * 64 + n * 16 + ec;
        float v = acc[m][n][j] * scale;
        if (BIAS)  v += bias[c];
        if (LRELU) v = v > 0.f ? v : 0.01f * v;
        if (EPI == 0)      ((float*)C)[r * (long)N + c] = v;
        else if (EPI == 1) ((u16*)C)[r * (long)N + c] = f2b(v);
        else               ((float*)C)[r * (long)N + c] += v;
      }
    }
  }
}

// distinct names so rocprof separates the shapes
__global__ __launch_bounds__(512, 1) void k_g256_up(
    const u16* __restrict__ A, const u16* __restrict__ B, void* __restrict__ C,
    const float* __restrict__ bias, int K, int N, float scale) {
  __shared__ u16 S[65536];
  g256_body<1, true, true>(S, A, B, C, bias, K, N, scale);
}
__global__ __launch_bounds__(512, 1) void k_g256_log(
    const u16* __restrict__ A, const u16* __restrict__ B, void* __restrict__ C,
    const float* __restrict__ bias, int K, int N, float scale) {
  __shared__ u16 S[65536];
  g256_body<0, false, false>(S, A, B, C, bias, K, N, scale);
}

extern "C" void kernel_launch(void* const* d_in, const int* in_sizes, int n_in,
                              void* d_out, int out_size, void* d_ws, size_t ws_size,
                              hipStream_t stream) {
  const int*   tokens = (const int*)d_in[0];
  const float* emb    = (const float*)d_in[1];
  const float* qk     = (const float*)d_in[2];
  const float* ov     = (const float*)d_in[3];
  const float* wup    = (const float*)d_in[4];
  const float* bup    = (const float*)d_in[5];
  const float* whid   = (const float*)d_in[6];
  const float* bhid   = (const float*)d_in[7];
  const float* wdown  = (const float*)d_in[8];
  const float* bdown  = (const float*)d_in[9];
  const float* g1     = (const float*)d_in[10];
  const float* b1     = (const float*)d_in[11];
  const float* g2     = (const float*)d_in[12];
  const float* b2     = (const float*)d_in[13];

  // scratch carved out of d_out (524 MB; only written by the final GEMM)
  char* Ob = (char*)d_out;
  float* scores = (float*)(Ob + 0);              // 33554432 B
  u16*   attn   = (u16*)(Ob + 33554432);         // 16777216 B
  u16*   m1     = (u16*)(Ob + 50331648);         // 33554432 B
  u16*   m2     = (u16*)(Ob + 83886080);         // 33554432 B
  u16*   qkT    = (u16*)(Ob + 117440512);        // 4 layers [1024][1024] bf16
  u16*   ovT    = (u16*)(Ob + 125829120);        // 4 layers
  u16*   upT    = (u16*)(Ob + 134217728);        // 4 layers [4096][1024]
  u16*   hidT   = (u16*)(Ob + 167772160);        // 4 layers [4096][4096]
  u16*   downT  = (u16*)(Ob + 301989888);        // 4 layers [1024][4096]
  float* xres   = (float*)(Ob + 335544320);      // residual f32 [4096][1024]
  u16*   h      = (u16*)(Ob + 352321536);        // LN out bf16
  u16*   hT     = (u16*)(Ob + 360710144);        // [2][1024][2048]
  u16*   q      = (u16*)(Ob + 369098752);        // [4096][1024]
  u16*   attnV  = (u16*)(Ob + 377487360);        // [4096][1024]

  // buffers live during the final GEMM go in d_ws
  u16* embB = (u16*)d_ws;                        // [32000][1024] bf16
  u16* xB   = (u16*)((char*)d_ws + 65536000);    // [4096][1024] bf16

  k_embed<<<dim3(BS), 256, 0, stream>>>(tokens, emb, xres);
  k_cvt<<<dim3(32000), 256, 0, stream>>>(emb, embB, 8192000);

  // all-layer batched weight transposes (z = layer), 64x64 tiles
  k_transpose64<float><<<dim3(16, 16, 4), 256, 0, stream>>>(qk,    qkT,   1024, 1024, 1048576,  1048576);
  k_transpose64<float><<<dim3(16, 16, 4), 256, 0, stream>>>(ov,    ovT,   1024, 1024, 1048576,  1048576);
  k_transpose64<float><<<dim3(64, 16, 4), 256, 0, stream>>>(wup,   upT,   1024, 4096, 4194304,  4194304);
  k_transpose64<float><<<dim3(64, 64, 4), 256, 0, stream>>>(whid,  hidT,  4096, 4096, 16777216, 16777216);
  k_transpose64<float><<<dim3(16, 64, 4), 256, 0, stream>>>(wdown, downT, 4096, 1024, 4194304,  4194304);

  for (int l = 0; l < 4; ++l) {
    // ---- attention ----
    k_ln<<<dim3(BS), 256, 0, stream>>>(xres, g1 + l * 1024, b1 + l * 1024, h);
    k_transpose64<u16><<<dim3(16, 32, 2), 256, 0, stream>>>(h, hT, 2048, 1024, 2048L * 1024, 1024L * 2048);
    // q = (h @ qk) / sqrt(d)
    k_gemm_bt<1, false, false, 0, false><<<dim3(32, 8, 1), 256, 0, stream>>>(
        h, qkT + (long)l * 1048576, q, nullptr, nullptr, 1024, 1024, 0, 0, 0, 0.03125f);
    // scores[z] = q[z] @ h[z]^T (upper-triangle blocks skipped)
    k_gemm_bt<0, false, false, 1, false><<<dim3(16, 16, 2), 256, 0, stream>>>(
        q, h, scores, nullptr, nullptr, 1024, 2048, 2048L * 1024, 2048L * 1024, 2048L * 2048, 1.f);
    k_softmax<<<dim3(2048, 2), 256, 0, stream>>>(scores, attn);
    // attnV[z] = attn[z] @ h[z] (K-loop causal-limited)
    k_gemm_bt<1, false, false, 2, false><<<dim3(16, 8, 2), 256, 0, stream>>>(
        attn, hT, attnV, nullptr, nullptr, 2048, 1024, 2048L * 2048, 1024L * 2048, 2048L * 1024, 1.f);
    // x += attnV @ ov
    k_gemm_bt<2, false, false, 0, false><<<dim3(32, 8, 1), 256, 0, stream>>>(
        attnV, ovT + (long)l * 1048576, xres, nullptr, nullptr, 1024, 1024, 0, 0, 0, 1.f);

    // ---- MLP ----
    k_ln<<<dim3(BS), 256, 0, stream>>>(xres, g2 + l * 1024, b2 + l * 1024, h);
    k_g256_up<<<dim3(16, 16), 512, 0, stream>>>(
        h, upT + (long)l * 4194304, m1, bup + l * 4096, 1024, 4096, 1.f);
    // hid on 128²+BK=128 (grid 1024 -> 2 blocks/CU resident; K=4096 benefits
    // most from the quartered barrier count — R11/R12-confirmed lever)
    k_gemm_bt<1, true, true, 0, false><<<dim3(32, 32, 1), 256, 0, stream>>>(
        m1, hidT + (long)l * 16777216, m2, bhid + l * 4096, nullptr, 4096, 4096, 0, 0, 0, 1.f);
    if (l == 3) {
      k_gemm_bt<2, true, true, 0, true><<<dim3(32, 8, 1), 256, 0, stream>>>(
          m2, downT + (long)l * 4194304, xres, bdown + l * 1024, xB, 4096, 1024, 0, 0, 0, 1.f);
    } else {
      k_gemm_bt<2, true, true, 0, false><<<dim3(32, 8, 1), 256, 0, stream>>>(
          m2, downT + (long)l * 4194304, xres, bdown + l * 1024, nullptr, 4096, 1024, 0, 0, 0, 1.f);
    }
  }

  // ---- logits = x @ emb^T ----
  k_g256_log<<<dim3(16, 125), 512, 0, stream>>>(
      xB, embB, (float*)d_out, nullptr, 1024, 32000, 1.f);
}

// Round 14
// 1992.145 us; speedup vs baseline: 1.1103x; 1.1103x over previous
//
#include <hip/hip_runtime.h>

#define BS   4096   // BATCH*SEQ
#define SEQL 2048
#define DM   1024
#define DH   4096
#define NV   32000

using u16 = unsigned short;

typedef __attribute__((ext_vector_type(8))) short bf16x8;
typedef __attribute__((ext_vector_type(4))) float f32x4;

__device__ __forceinline__ u16 f2b(float f) {
  union { float f; unsigned u; } c; c.f = f;
  unsigned u = c.u;
  u = (u + 0x7FFFu + ((u >> 16) & 1u)) >> 16;
  return (u16)u;
}

__device__ __forceinline__ void gld16(const u16* g, u16* l) {
  __builtin_amdgcn_global_load_lds(
      (__attribute__((address_space(1))) void*)(void*)const_cast<u16*>(g),
      (__attribute__((address_space(3))) void*)l, 16, 0, 0);
}

// ---------------- embed ----------------
__global__ __launch_bounds__(256) void k_embed(const int* __restrict__ tok,
                                               const float* __restrict__ emb,
                                               float* __restrict__ x) {
  const long row = blockIdx.x;
  const long e = tok[row];
  ((float4*)(x + row * DM))[threadIdx.x] = ((const float4*)(emb + e * DM))[threadIdx.x];
}

// ---------------- f32 -> bf16 convert ----------------
__global__ __launch_bounds__(256) void k_cvt(const float* __restrict__ in,
                                             u16* __restrict__ out, int n4) {
  int i = blockIdx.x * 256 + threadIdx.x;
  if (i < n4) {
    float4 v = ((const float4*)in)[i];
    ushort4 o;
    o.x = f2b(v.x); o.y = f2b(v.y); o.z = f2b(v.z); o.w = f2b(v.w);
    ((ushort4*)out)[i] = o;
  }
}

// ---------------- LayerNorm ----------------
__global__ __launch_bounds__(256) void k_ln(const float* __restrict__ x,
                                            const float* __restrict__ g,
                                            const float* __restrict__ b,
                                            u16* __restrict__ out) {
  const long row = blockIdx.x;
  const int t = threadIdx.x;
  float4 v = ((const float4*)(x + row * DM))[t];
  float s  = v.x + v.y + v.z + v.w;
  float q2 = v.x*v.x + v.y*v.y + v.z*v.z + v.w*v.w;
#pragma unroll
  for (int o = 1; o < 64; o <<= 1) { s += __shfl_xor(s, o); q2 += __shfl_xor(q2, o); }
  __shared__ float rs_[4], rq_[4];
  const int lane = t & 63, wid = t >> 6;
  if (lane == 0) { rs_[wid] = s; rq_[wid] = q2; }
  __syncthreads();
  s  = rs_[0] + rs_[1] + rs_[2] + rs_[3];
  q2 = rq_[0] + rq_[1] + rq_[2] + rq_[3];
  const float mu   = s * (1.f / 1024.f);
  const float var  = q2 * (1.f / 1024.f) - mu * mu;
  const float rstd = rsqrtf(var + 1e-5f);
  float4 gg = ((const float4*)g)[t];
  float4 bb = ((const float4*)b)[t];
  ushort4 o;
  o.x = f2b((v.x - mu) * rstd * gg.x + bb.x);
  o.y = f2b((v.y - mu) * rstd * gg.y + bb.y);
  o.z = f2b((v.z - mu) * rstd * gg.z + bb.z);
  o.w = f2b((v.w - mu) * rstd * gg.w + bb.w);
  ((ushort4*)(out + row * DM))[t] = o;
}

// ---------------- 64x64 tiled transpose, optional f32->bf16 ----------------
__device__ __forceinline__ u16 to_b16(float v) { return f2b(v); }
__device__ __forceinline__ u16 to_b16(u16 v)   { return v; }

template <typename T>
__global__ __launch_bounds__(256) void k_transpose64(const T* __restrict__ in,
                                                     u16* __restrict__ out,
                                                     int R, int C, long inz, long outz) {
  __shared__ u16 tile[64][65];
  const T* ip = in + (long)blockIdx.z * inz;
  u16* op = out + (long)blockIdx.z * outz;
  const int tx = threadIdx.x & 63, ty = threadIdx.x >> 6;
  const long c0 = (long)blockIdx.x * 64, r0 = (long)blockIdx.y * 64;
#pragma unroll
  for (int i = 0; i < 16; ++i)
    tile[ty + i * 4][tx] = to_b16(ip[(r0 + ty + i * 4) * C + c0 + tx]);
  __syncthreads();
#pragma unroll
  for (int i = 0; i < 16; ++i)
    op[(c0 + ty + i * 4) * R + r0 + tx] = tile[tx][ty + i * 4];
}

// ---------------- causal row softmax (work limited to <= r) ----------------
__global__ __launch_bounds__(256) void k_softmax(const float* __restrict__ sc,
                                                 u16* __restrict__ at) {
  const int r = blockIdx.x;
  const long z = blockIdx.y;
  const int t = threadIdx.x;
  const float* row = sc + (z * SEQL + r) * SEQL;
  u16* orow = at + (z * SEQL + r) * SEQL;
  const int ni = (r >> 8) + 1;
  float vals[8];
  float mx = -3.4e38f;
  for (int i = 0; i < ni; ++i) {
    int c = i * 256 + t;
    float v = (c <= r) ? row[c] : -3.4e38f;
    vals[i] = v;
    mx = fmaxf(mx, v);
  }
#pragma unroll
  for (int o = 1; o < 64; o <<= 1) mx = fmaxf(mx, __shfl_xor(mx, o));
  __shared__ float rm[4], rsum[4];
  const int lane = t & 63, wid = t >> 6;
  if (lane == 0) rm[wid] = mx;
  __syncthreads();
  mx = fmaxf(fmaxf(rm[0], rm[1]), fmaxf(rm[2], rm[3]));
  float sum = 0.f;
  for (int i = 0; i < ni; ++i) {
    int c = i * 256 + t;
    float e = (c <= r) ? __expf(vals[i] - mx) : 0.f;
    vals[i] = e;
    sum += e;
  }
#pragma unroll
  for (int o = 1; o < 64; o <<= 1) sum += __shfl_xor(sum, o);
  if (lane == 0) rsum[wid] = sum;
  __syncthreads();
  sum = rsum[0] + rsum[1] + rsum[2] + rsum[3];
  const float inv = 1.f / sum;
  for (int i = 0; i < ni; ++i) orow[i * 256 + t] = f2b(vals[i] * inv);
}

// ---------------- 128x128 bf16 GEMM, BK=128 (four [128][32] half-tiles) -----
// Quarters barrier frequency vs BK=32 (one barrier pair per 128 K-elems).
// Conflict-free 64B-row half-tile layout; 64KB LDS (2 blocks/CU); ascending-k
// accumulation -> bit-identical output.
template <int EPI, bool BIAS, bool LRELU, int CAUSAL, bool XOUT>
__global__ __launch_bounds__(256, 2) void k_gemm_bt(
    const u16* __restrict__ A, const u16* __restrict__ B, void* __restrict__ C,
    const float* __restrict__ bias, u16* __restrict__ xb, int K, int N,
    long sAz, long sBz, long sCz, float scale) {
  __shared__ u16 lA[4][128 * 32];
  __shared__ u16 lB[4][128 * 32];
  const int t = threadIdx.x;
  const long z = blockIdx.z;
  const long row0 = (long)blockIdx.x * 128;
  const long col0 = (long)blockIdx.y * 128;
  if (CAUSAL == 1 && col0 > row0 + 127) return;
  const int Klim = (CAUSAL == 2) ? min(K, (int)row0 + 128) : K;
  const u16* Ab = A + z * sAz;
  const u16* Bb = B + z * sBz;

  const int rr = t >> 2;           // 0..63
  const int c8 = (t & 3) * 8;      // 0,8,16,24
  const u16* gA0 = Ab + (row0 + rr) * K + c8;
  const u16* gA1 = Ab + (row0 + 64 + rr) * K + c8;
  const u16* gB0 = Bb + (col0 + rr) * K + c8;
  const u16* gB1 = Bb + (col0 + 64 + rr) * K + c8;
  const int so0 = rr * 32 + c8;
  const int so1 = (64 + rr) * 32 + c8;

  const int lane = t & 63;
  const int w = t >> 6;
  const int wr = (w >> 1) * 64, wc = (w & 1) * 64;
  const int fr = lane & 15;
  const int fk = (lane >> 4) * 8;

  f32x4 acc[4][4] = {};

  for (int k0 = 0; k0 < Klim; k0 += 128) {
#pragma unroll
    for (int q = 0; q < 4; ++q) {
      gld16(gA0 + k0 + q * 32, &lA[q][so0]);
      gld16(gA1 + k0 + q * 32, &lA[q][so1]);
      gld16(gB0 + k0 + q * 32, &lB[q][so0]);
      gld16(gB1 + k0 + q * 32, &lB[q][so1]);
    }
    __syncthreads();
#pragma unroll
    for (int kh = 0; kh < 4; ++kh) {
      bf16x8 av[4], bv[4];
#pragma unroll
      for (int m = 0; m < 4; ++m) av[m] = *(const bf16x8*)&lA[kh][(wr + m * 16 + fr) * 32 + fk];
#pragma unroll
      for (int n = 0; n < 4; ++n) bv[n] = *(const bf16x8*)&lB[kh][(wc + n * 16 + fr) * 32 + fk];
#pragma unroll
      for (int m = 0; m < 4; ++m)
#pragma unroll
        for (int n = 0; n < 4; ++n)
          acc[m][n] = __builtin_amdgcn_mfma_f32_16x16x32_bf16(av[m], bv[n], acc[m][n], 0, 0, 0);
    }
    __syncthreads();
  }

  const int er = (lane >> 4) * 4;
  const int ec = lane & 15;
#pragma unroll
  for (int m = 0; m < 4; ++m) {
#pragma unroll
    for (int n = 0; n < 4; ++n) {
#pragma unroll
      for (int j = 0; j < 4; ++j) {
        long r = row0 + wr + m * 16 + er + j;
        long c = col0 + wc + n * 16 + ec;
        float v = acc[m][n][j] * scale;
        if (BIAS)  v += bias[c];
        if (LRELU) v = v > 0.f ? v : 0.01f * v;
        long idx = z * sCz + r * (long)N + c;
        if (EPI == 0)      ((float*)C)[idx] = v;
        else if (EPI == 1) ((u16*)C)[idx] = f2b(v);
        else {
          float nv = ((float*)C)[idx] + v;
          ((float*)C)[idx] = nv;
          if (XOUT) xb[idx] = f2b(nv);
        }
      }
    }
  }
}

// ---------------- 256x256 BK=64 8-wave bf16 GEMM, m201-faithful phases ------
// (R8 configuration — best verified for the 1-block/CU 256² shapes.)
template <int EPI, bool BIAS, bool LRELU>
__device__ __forceinline__ void g256_body(
    u16* S, const u16* __restrict__ A, const u16* __restrict__ B,
    void* __restrict__ C, const float* __restrict__ bias, int K, int N, float scale) {
  char* Sc = (char*)S;
  const int t = threadIdx.x;
  const int lane = t & 63;
  const int w = t >> 6;
  const int wr = w >> 2;           // 0..1  (M half)
  const int wc = w & 3;            // 0..3  (N quarter)
  const long row0 = (long)blockIdx.x * 256;
  const long col0 = (long)blockIdx.y * 256;
  const int nt = K >> 6;

  int srow[2], scol[2], ldsb[2];
#pragma unroll
  for (int i = 0; i < 2; ++i) {
    int d = t * 16 + i * 8192;
    int dx = d ^ (((d >> 7) & 3) << 4);
    srow[i] = dx >> 6;
    scol[i] = (dx & 63) >> 1;
    ldsb[i] = d;
  }
  const u16* Abase = A + row0 * (long)K;
  const u16* Bbase = B + col0 * (long)K;

  auto stage = [&](int opb, int kh, int buf, int kb) {
#pragma unroll
    for (int i = 0; i < 2; ++i) {
      const u16* src = (opb ? Bbase : Abase) + (long)srow[i] * K + kb + kh * 32 + scol[i];
      u16* dst = &S[(buf * 4 + opb * 2 + kh) * 8192 + (ldsb[i] >> 1)];
      gld16(src, dst);
    }
  };

  const int fr = lane & 15;
  const int fky = lane >> 4;
  const int axor = ((fr >> 1) & 3) << 4;
  int aoff[8], boff[4];
#pragma unroll
  for (int m = 0; m < 8; ++m)
    aoff[m] = (((wr * 128 + m * 16 + fr) * 64) + fky * 16) ^ axor;
#pragma unroll
  for (int n = 0; n < 4; ++n)
    boff[n] = (((wc * 64 + n * 16 + fr) * 64) + fky * 16) ^ axor;

  f32x4 acc[8][4] = {};
  bf16x8 av0, av1, av2, av3;
  bf16x8 bX0, bX1, bX2, bX3, bY0, bY1, bY2, bY3;

#define RD_A(bb, kh, mh)                                                   \
  { const char* Ah_ = Sc + (bb) * 65536 + (kh) * 16384;                    \
    av0 = *(const bf16x8*)(Ah_ + aoff[(mh) * 4 + 0]);                      \
    av1 = *(const bf16x8*)(Ah_ + aoff[(mh) * 4 + 1]);                      \
    av2 = *(const bf16x8*)(Ah_ + aoff[(mh) * 4 + 2]);                      \
    av3 = *(const bf16x8*)(Ah_ + aoff[(mh) * 4 + 3]); }
#define RD_B(d0, d1, d2, d3, bb, kh)                                       \
  { const char* Bh_ = Sc + (bb) * 65536 + 32768 + (kh) * 16384;            \
    d0 = *(const bf16x8*)(Bh_ + boff[0]);                                  \
    d1 = *(const bf16x8*)(Bh_ + boff[1]);                                  \
    d2 = *(const bf16x8*)(Bh_ + boff[2]);                                  \
    d3 = *(const bf16x8*)(Bh_ + boff[3]); }
#define WAIT_LGKM()                                                        \
  asm volatile("s_waitcnt lgkmcnt(0)" ::: "memory");                       \
  __builtin_amdgcn_sched_barrier(0);
#define MF16(b0, b1, b2, b3, mh)                                                                     \
  __builtin_amdgcn_s_setprio(1);                                                                     \
  acc[(mh)*4+0][0] = __builtin_amdgcn_mfma_f32_16x16x32_bf16(av0, b0, acc[(mh)*4+0][0], 0, 0, 0);    \
  acc[(mh)*4+0][1] = __builtin_amdgcn_mfma_f32_16x16x32_bf16(av0, b1, acc[(mh)*4+0][1], 0, 0, 0);    \
  acc[(mh)*4+0][2] = __builtin_amdgcn_mfma_f32_16x16x32_bf16(av0, b2, acc[(mh)*4+0][2], 0, 0, 0);    \
  acc[(mh)*4+0][3] = __builtin_amdgcn_mfma_f32_16x16x32_bf16(av0, b3, acc[(mh)*4+0][3], 0, 0, 0);    \
  acc[(mh)*4+1][0] = __builtin_amdgcn_mfma_f32_16x16x32_bf16(av1, b0, acc[(mh)*4+1][0], 0, 0, 0);    \
  acc[(mh)*4+1][1] = __builtin_amdgcn_mfma_f32_16x16x32_bf16(av1, b1, acc[(mh)*4+1][1], 0, 0, 0);    \
  acc[(mh)*4+1][2] = __builtin_amdgcn_mfma_f32_16x16x32_bf16(av1, b2, acc[(mh)*4+1][2], 0, 0, 0);    \
  acc[(mh)*4+1][3] = __builtin_amdgcn_mfma_f32_16x16x32_bf16(av1, b3, acc[(mh)*4+1][3], 0, 0, 0);    \
  acc[(mh)*4+2][0] = __builtin_amdgcn_mfma_f32_16x16x32_bf16(av2, b0, acc[(mh)*4+2][0], 0, 0, 0);    \
  acc[(mh)*4+2][1] = __builtin_amdgcn_mfma_f32_16x16x32_bf16(av2, b1, acc[(mh)*4+2][1], 0, 0, 0);    \
  acc[(mh)*4+2][2] = __builtin_amdgcn_mfma_f32_16x16x32_bf16(av2, b2, acc[(mh)*4+2][2], 0, 0, 0);    \
  acc[(mh)*4+2][3] = __builtin_amdgcn_mfma_f32_16x16x32_bf16(av2, b3, acc[(mh)*4+2][3], 0, 0, 0);    \
  acc[(mh)*4+3][0] = __builtin_amdgcn_mfma_f32_16x16x32_bf16(av3, b0, acc[(mh)*4+3][0], 0, 0, 0);    \
  acc[(mh)*4+3][1] = __builtin_amdgcn_mfma_f32_16x16x32_bf16(av3, b1, acc[(mh)*4+3][1], 0, 0, 0);    \
  acc[(mh)*4+3][2] = __builtin_amdgcn_mfma_f32_16x16x32_bf16(av3, b2, acc[(mh)*4+3][2], 0, 0, 0);    \
  acc[(mh)*4+3][3] = __builtin_amdgcn_mfma_f32_16x16x32_bf16(av3, b3, acc[(mh)*4+3][3], 0, 0, 0);    \
  __builtin_amdgcn_s_setprio(0);

  // prologue: stage tile 0; wait kh0 halves (4 remain outstanding)
  stage(0, 0, 0, 0);
  stage(1, 0, 0, 0);
  stage(0, 1, 0, 0);
  stage(1, 1, 0, 0);
  asm volatile("s_waitcnt vmcnt(4)" ::: "memory");
  __builtin_amdgcn_s_barrier();

  int cur = 0;
  for (int tt = 0; tt < nt; ++tt) {
    const int knext = (tt + 1 < nt ? tt + 1 : tt) * 64;
    const int nx = cur ^ 1;
    // ph1: (kh0,mh0) — stage A-kh0 -> nxt
    RD_A(cur, 0, 0);
    RD_B(bX0, bX1, bX2, bX3, cur, 0);
    stage(0, 0, nx, knext);
    __builtin_amdgcn_s_barrier();
    WAIT_LGKM();
    MF16(bX0, bX1, bX2, bX3, 0);
    __builtin_amdgcn_s_barrier();
    // ph2: (kh0,mh1) — stage B-kh0 -> nxt
    RD_A(cur, 0, 1);
    stage(1, 0, nx, knext);
    __builtin_amdgcn_s_barrier();
    WAIT_LGKM();
    MF16(bX0, bX1, bX2, bX3, 1);
    asm volatile("s_waitcnt vmcnt(4)" ::: "memory");   // kh1(cur) landed
    __builtin_amdgcn_s_barrier();
    // ph3: (kh1,mh0) — stage A-kh1 -> nxt
    RD_A(cur, 1, 0);
    RD_B(bY0, bY1, bY2, bY3, cur, 1);
    stage(0, 1, nx, knext);
    __builtin_amdgcn_s_barrier();
    WAIT_LGKM();
    MF16(bY0, bY1, bY2, bY3, 0);
    __builtin_amdgcn_s_barrier();
    // ph4: (kh1,mh1) — stage B-kh1 -> nxt
    RD_A(cur, 1, 1);
    stage(1, 1, nx, knext);
    __builtin_amdgcn_s_barrier();
    WAIT_LGKM();
    MF16(bY0, bY1, bY2, bY3, 1);
    asm volatile("s_waitcnt vmcnt(4)" ::: "memory");   // kh0(next) landed
    __builtin_amdgcn_s_barrier();
    cur = nx;
  }
  asm volatile("s_waitcnt vmcnt(0)" ::: "memory");
#undef RD_A
#undef RD_B
#undef WAIT_LGKM
#undef MF16

  const int er = (lane >> 4) * 4;
  const int ec = lane & 15;
#pragma unroll
  for (int m = 0; m < 8; ++m) {
#pragma unroll
    for (int n = 0; n < 4; ++n) {
#pragma unroll
      for (int j = 0; j < 4; ++j) {
        long r = row0 + wr * 128 + m * 16 + er + j;
        long c = col0 + wc * 64 + n * 16 + ec;
        float v = acc[m][n][j] * scale;
        if (BIAS)  v += bias[c];
        if (LRELU) v = v > 0.f ? v : 0.01f * v;
        if (EPI == 0)      ((float*)C)[r * (long)N + c] = v;
        else if (EPI == 1) ((u16*)C)[r * (long)N + c] = f2b(v);
        else               ((float*)C)[r * (long)N + c] += v;
      }
    }
  }
}

// distinct names so rocprof separates the shapes
__global__ __launch_bounds__(512, 1) void k_g256_up(
    const u16* __restrict__ A, const u16* __restrict__ B, void* __restrict__ C,
    const float* __restrict__ bias, int K, int N, float scale) {
  __shared__ u16 S[65536];
  g256_body<1, true, true>(S, A, B, C, bias, K, N, scale);
}
__global__ __launch_bounds__(512, 1) void k_g256_hid(
    const u16* __restrict__ A, const u16* __restrict__ B, void* __restrict__ C,
    const float* __restrict__ bias, int K, int N, float scale) {
  __shared__ u16 S[65536];
  g256_body<1, true, true>(S, A, B, C, bias, K, N, scale);
}
__global__ __launch_bounds__(512, 1) void k_g256_log(
    const u16* __restrict__ A, const u16* __restrict__ B, void* __restrict__ C,
    const float* __restrict__ bias, int K, int N, float scale) {
  __shared__ u16 S[65536];
  g256_body<0, false, false>(S, A, B, C, bias, K, N, scale);
}

extern "C" void kernel_launch(void* const* d_in, const int* in_sizes, int n_in,
                              void* d_out, int out_size, void* d_ws, size_t ws_size,
                              hipStream_t stream) {
  const int*   tokens = (const int*)d_in[0];
  const float* emb    = (const float*)d_in[1];
  const float* qk     = (const float*)d_in[2];
  const float* ov     = (const float*)d_in[3];
  const float* wup    = (const float*)d_in[4];
  const float* bup    = (const float*)d_in[5];
  const float* whid   = (const float*)d_in[6];
  const float* bhid   = (const float*)d_in[7];
  const float* wdown  = (const float*)d_in[8];
  const float* bdown  = (const float*)d_in[9];
  const float* g1     = (const float*)d_in[10];
  const float* b1     = (const float*)d_in[11];
  const float* g2     = (const float*)d_in[12];
  const float* b2     = (const float*)d_in[13];

  // scratch carved out of d_out (524 MB; only written by the final GEMM)
  char* Ob = (char*)d_out;
  float* scores = (float*)(Ob + 0);              // 33554432 B
  u16*   attn   = (u16*)(Ob + 33554432);         // 16777216 B
  u16*   m1     = (u16*)(Ob + 50331648);         // 33554432 B
  u16*   m2     = (u16*)(Ob + 83886080);         // 33554432 B
  u16*   qkT    = (u16*)(Ob + 117440512);        // 4 layers [1024][1024] bf16
  u16*   ovT    = (u16*)(Ob + 125829120);        // 4 layers
  u16*   upT    = (u16*)(Ob + 134217728);        // 4 layers [4096][1024]
  u16*   hidT   = (u16*)(Ob + 167772160);        // 4 layers [4096][4096]
  u16*   downT  = (u16*)(Ob + 301989888);        // 4 layers [1024][4096]
  float* xres   = (float*)(Ob + 335544320);      // residual f32 [4096][1024]
  u16*   h      = (u16*)(Ob + 352321536);        // LN out bf16
  u16*   hT     = (u16*)(Ob + 360710144);        // [2][1024][2048]
  u16*   q      = (u16*)(Ob + 369098752);        // [4096][1024]
  u16*   attnV  = (u16*)(Ob + 377487360);        // [4096][1024]

  // buffers live during the final GEMM go in d_ws
  u16* embB = (u16*)d_ws;                        // [32000][1024] bf16
  u16* xB   = (u16*)((char*)d_ws + 65536000);    // [4096][1024] bf16

  k_embed<<<dim3(BS), 256, 0, stream>>>(tokens, emb, xres);
  k_cvt<<<dim3(32000), 256, 0, stream>>>(emb, embB, 8192000);

  // all-layer batched weight transposes (z = layer), 64x64 tiles
  k_transpose64<float><<<dim3(16, 16, 4), 256, 0, stream>>>(qk,    qkT,   1024, 1024, 1048576,  1048576);
  k_transpose64<float><<<dim3(16, 16, 4), 256, 0, stream>>>(ov,    ovT,   1024, 1024, 1048576,  1048576);
  k_transpose64<float><<<dim3(64, 16, 4), 256, 0, stream>>>(wup,   upT,   1024, 4096, 4194304,  4194304);
  k_transpose64<float><<<dim3(64, 64, 4), 256, 0, stream>>>(whid,  hidT,  4096, 4096, 16777216, 16777216);
  k_transpose64<float><<<dim3(16, 64, 4), 256, 0, stream>>>(wdown, downT, 4096, 1024, 4194304,  4194304);

  for (int l = 0; l < 4; ++l) {
    // ---- attention ----
    k_ln<<<dim3(BS), 256, 0, stream>>>(xres, g1 + l * 1024, b1 + l * 1024, h);
    k_transpose64<u16><<<dim3(16, 32, 2), 256, 0, stream>>>(h, hT, 2048, 1024, 2048L * 1024, 1024L * 2048);
    // q = (h @ qk) / sqrt(d)
    k_gemm_bt<1, false, false, 0, false><<<dim3(32, 8, 1), 256, 0, stream>>>(
        h, qkT + (long)l * 1048576, q, nullptr, nullptr, 1024, 1024, 0, 0, 0, 0.03125f);
    // scores[z] = q[z] @ h[z]^T (upper-triangle blocks skipped)
    k_gemm_bt<0, false, false, 1, false><<<dim3(16, 16, 2), 256, 0, stream>>>(
        q, h, scores, nullptr, nullptr, 1024, 2048, 2048L * 1024, 2048L * 1024, 2048L * 2048, 1.f);
    k_softmax<<<dim3(2048, 2), 256, 0, stream>>>(scores, attn);
    // attnV[z] = attn[z] @ h[z] (K-loop causal-limited)
    k_gemm_bt<1, false, false, 2, false><<<dim3(16, 8, 2), 256, 0, stream>>>(
        attn, hT, attnV, nullptr, nullptr, 2048, 1024, 2048L * 2048, 1024L * 2048, 2048L * 1024, 1.f);
    // x += attnV @ ov
    k_gemm_bt<2, false, false, 0, false><<<dim3(32, 8, 1), 256, 0, stream>>>(
        attnV, ovT + (long)l * 1048576, xres, nullptr, nullptr, 1024, 1024, 0, 0, 0, 1.f);

    // ---- MLP ----
    k_ln<<<dim3(BS), 256, 0, stream>>>(xres, g2 + l * 1024, b2 + l * 1024, h);
    k_g256_up<<<dim3(16, 16), 512, 0, stream>>>(
        h, upT + (long)l * 4194304, m1, bup + l * 4096, 1024, 4096, 1.f);
    k_g256_hid<<<dim3(16, 16), 512, 0, stream>>>(
        m1, hidT + (long)l * 16777216, m2, bhid + l * 4096, 4096, 4096, 1.f);
    if (l == 3) {
      k_gemm_bt<2, true, true, 0, true><<<dim3(32, 8, 1), 256, 0, stream>>>(
          m2, downT + (long)l * 4194304, xres, bdown + l * 1024, xB, 4096, 1024, 0, 0, 0, 1.f);
    } else {
      k_gemm_bt<2, true, true, 0, false><<<dim3(32, 8, 1), 256, 0, stream>>>(
          m2, downT + (long)l * 4194304, xres, bdown + l * 1024, nullptr, 4096, 1024, 0, 0, 0, 1.f);
    }
  }

  // ---- logits = x @ emb^T ----
  k_g256_log<<<dim3(16, 125), 512, 0, stream>>>(
      xB, embB, (float*)d_out, nullptr, 1024, 32000, 1.f);
}